// Round 8
// baseline (409.947 us; speedup 1.0000x reference)
//
#include <hip/hip_runtime.h>
#include <hip/hip_cooperative_groups.h>
#include <cstdint>
#include <cstddef>

namespace cg = cooperative_groups;

#define C_DIM 256
#define N_PIX 10000
#define B_SZ 16

struct KParams {
  const float *x, *Wc, *bc, *Wb, *bb;
  const float *dW1, *db1, *dW2, *db2, *dW3, *db3;
  const float *rW1, *rb1, *rW2, *rb2, *rW3, *rb3;
  const float *det_q, *rec_q, *pe;
  float *cls, *bbox, *conf, *wpe, *wT, *det, *rec;
  unsigned long long* candbuf;
  unsigned int* cnt;
  int* idx;
};

union SMem {
  float w[6][C_DIM];                                   // heads
  float tile[64][65];                                  // prep transpose
  struct {
    unsigned int ordl[1250];
    unsigned int whist[4][256];
    unsigned int hist[256];
    unsigned int s[4];                                 // 0=cnt 1=prefix 2=nc
  } t1;
  struct {
    unsigned long long keys[4096];
    unsigned int whist[4][256];
    unsigned int hist[256];
    unsigned long long cand2[256];
    unsigned int s[4];
  } t2;
  struct { float A[8][C_DIM]; float B[8][C_DIM]; } mlp;
};

// ---------------- shared device helpers -------------------------------------------------
__device__ __forceinline__ void mlp_layer8(const float (*in)[C_DIM], float (*outb)[C_DIM],
    const float* __restrict__ Wl, const float* __restrict__ bias, bool relu, int og, int lr0) {
  float4 bv = *(const float4*)(bias + og * 4);
  float4 a0 = bv, a1 = bv;
  const float* i0p = in[lr0];
  const float* i1p = in[lr0 + 1];
#pragma unroll 4
  for (int cq = 0; cq < 64; ++cq) {
    int c = cq * 4;
    float4 i0 = *(const float4*)(i0p + c);
    float4 i1 = *(const float4*)(i1p + c);
    float4 w0 = *(const float4*)(Wl + (size_t)(c + 0) * C_DIM + og * 4);
    float4 w1 = *(const float4*)(Wl + (size_t)(c + 1) * C_DIM + og * 4);
    float4 w2 = *(const float4*)(Wl + (size_t)(c + 2) * C_DIM + og * 4);
    float4 w3 = *(const float4*)(Wl + (size_t)(c + 3) * C_DIM + og * 4);
    a0.x = fmaf(w0.x, i0.x, a0.x); a0.y = fmaf(w0.y, i0.x, a0.y);
    a0.z = fmaf(w0.z, i0.x, a0.z); a0.w = fmaf(w0.w, i0.x, a0.w);
    a0.x = fmaf(w1.x, i0.y, a0.x); a0.y = fmaf(w1.y, i0.y, a0.y);
    a0.z = fmaf(w1.z, i0.y, a0.z); a0.w = fmaf(w1.w, i0.y, a0.w);
    a0.x = fmaf(w2.x, i0.z, a0.x); a0.y = fmaf(w2.y, i0.z, a0.y);
    a0.z = fmaf(w2.z, i0.z, a0.z); a0.w = fmaf(w2.w, i0.z, a0.w);
    a0.x = fmaf(w3.x, i0.w, a0.x); a0.y = fmaf(w3.y, i0.w, a0.y);
    a0.z = fmaf(w3.z, i0.w, a0.z); a0.w = fmaf(w3.w, i0.w, a0.w);
    a1.x = fmaf(w0.x, i1.x, a1.x); a1.y = fmaf(w0.y, i1.x, a1.y);
    a1.z = fmaf(w0.z, i1.x, a1.z); a1.w = fmaf(w0.w, i1.x, a1.w);
    a1.x = fmaf(w1.x, i1.y, a1.x); a1.y = fmaf(w1.y, i1.y, a1.y);
    a1.z = fmaf(w1.z, i1.y, a1.z); a1.w = fmaf(w1.w, i1.y, a1.w);
    a1.x = fmaf(w2.x, i1.z, a1.x); a1.y = fmaf(w2.y, i1.z, a1.y);
    a1.z = fmaf(w2.z, i1.z, a1.z); a1.w = fmaf(w2.w, i1.z, a1.w);
    a1.x = fmaf(w3.x, i1.w, a1.x); a1.y = fmaf(w3.y, i1.w, a1.y);
    a1.z = fmaf(w3.z, i1.w, a1.z); a1.w = fmaf(w3.w, i1.w, a1.w);
  }
  if (relu) {
    a0.x = fmaxf(a0.x, 0.f); a0.y = fmaxf(a0.y, 0.f); a0.z = fmaxf(a0.z, 0.f); a0.w = fmaxf(a0.w, 0.f);
    a1.x = fmaxf(a1.x, 0.f); a1.y = fmaxf(a1.y, 0.f); a1.z = fmaxf(a1.z, 0.f); a1.w = fmaxf(a1.w, 0.f);
  }
  *(float4*)(&outb[lr0][og * 4]) = a0;
  *(float4*)(&outb[lr0 + 1][og * 4]) = a1;
  __syncthreads();
}

__device__ __forceinline__ float pos_bilinear(const float* __restrict__ pe, int c, int n) {
  int y = n / 100, xq = n % 100;
  float sy = fminf(fmaxf((y + 0.5f) * 0.5f - 0.5f, 0.0f), 49.0f);
  float sx = fminf(fmaxf((xq + 0.5f) * 0.5f - 0.5f, 0.0f), 49.0f);
  int y0 = (int)floorf(sy); int y1 = min(y0 + 1, 49); float ty = sy - (float)y0;
  int x0i = (int)floorf(sx); int x1i = min(x0i + 1, 49); float tx = sx - (float)x0i;
  const float* p = pe + (size_t)c * 2500;
  float v00 = p[y0 * 50 + x0i], v01 = p[y0 * 50 + x1i];
  float v10 = p[y1 * 50 + x0i], v11 = p[y1 * 50 + x1i];
  float rr0 = v00 * (1.0f - ty) + v10 * ty;
  float rr1 = v01 * (1.0f - ty) + v11 * ty;
  return rr0 * (1.0f - tx) + rr1 * tx;
}

// ================== fused cooperative kernel =============================================
__global__ __launch_bounds__(256, 2) void k_fused(KParams P) {
  __shared__ SMem sm;
  cg::grid_group grid = cg::this_grid();
  int tid = threadIdx.x;
  int bid = blockIdx.x;
  int nblk = gridDim.x;   // 512

  // ---- phase A: wpe (blocks 0..59) + weight transpose (60..155) ----
  if (bid < 60) {
    int o = bid / 10;
    int p = (bid % 10) * 256 + tid;
    if (p < 2500) {
      const float* W = (o < 2) ? (P.Wc + o * C_DIM) : (P.Wb + (o - 2) * C_DIM);
      float acc = 0.f;
#pragma unroll 8
      for (int c = 0; c < C_DIM; ++c) acc = fmaf(W[c], P.pe[c * 2500 + p], acc);
      P.wpe[o * 2500 + p] = acc;
    }
  } else if (bid < 156) {
    int t = bid - 60;
    int m = t >> 4;
    int tl = t & 15;
    int ty = tl >> 2, tx = tl & 3;
    const float* W;
    switch (m) {
      case 0: W = P.dW1; break;
      case 1: W = P.dW2; break;
      case 2: W = P.dW3; break;
      case 3: W = P.rW1; break;
      case 4: W = P.rW2; break;
      default: W = P.rW3; break;
    }
    int lane = tid & 63, rg = tid >> 6;
    for (int rr = rg; rr < 64; rr += 4)
      sm.tile[rr][lane] = W[(size_t)(ty * 64 + rr) * 256 + tx * 64 + lane];
    __syncthreads();
    for (int rr = rg; rr < 64; rr += 4)
      P.wT[(size_t)m * 65536 + (size_t)(tx * 64 + rr) * 256 + ty * 64 + lane] = sm.tile[lane][rr];
  }
  grid.sync();

  // ---- phase B: heads (grid-stride over 640 tiles) ----
  sm.w[0][tid] = P.Wc[tid];
  sm.w[1][tid] = P.Wc[C_DIM + tid];
  sm.w[2][tid] = P.Wb[tid];
  sm.w[3][tid] = P.Wb[C_DIM + tid];
  sm.w[4][tid] = P.Wb[2 * C_DIM + tid];
  sm.w[5][tid] = P.Wb[3 * C_DIM + tid];
  __syncthreads();
  for (int t = bid; t < 640; t += nblk) {
    int txile = t % 40, b = t / 40;
    int n = txile * 256 + tid;
    if (n < N_PIX) {
      const float* xb = P.x + (size_t)b * C_DIM * N_PIX + n;
      float a0 = 0.f, a1 = 0.f, a2 = 0.f, a3 = 0.f, a4 = 0.f, a5 = 0.f;
#pragma unroll 4
      for (int c = 0; c < C_DIM; c += 4) {
        float x0 = xb[(size_t)(c + 0) * N_PIX];
        float x1 = xb[(size_t)(c + 1) * N_PIX];
        float x2 = xb[(size_t)(c + 2) * N_PIX];
        float x3 = xb[(size_t)(c + 3) * N_PIX];
        float4 w0 = *(const float4*)(&sm.w[0][c]);
        float4 w1 = *(const float4*)(&sm.w[1][c]);
        float4 w2 = *(const float4*)(&sm.w[2][c]);
        float4 w3 = *(const float4*)(&sm.w[3][c]);
        float4 w4 = *(const float4*)(&sm.w[4][c]);
        float4 w5 = *(const float4*)(&sm.w[5][c]);
        a0 = fmaf(w0.x, x0, a0); a0 = fmaf(w0.y, x1, a0); a0 = fmaf(w0.z, x2, a0); a0 = fmaf(w0.w, x3, a0);
        a1 = fmaf(w1.x, x0, a1); a1 = fmaf(w1.y, x1, a1); a1 = fmaf(w1.z, x2, a1); a1 = fmaf(w1.w, x3, a1);
        a2 = fmaf(w2.x, x0, a2); a2 = fmaf(w2.y, x1, a2); a2 = fmaf(w2.z, x2, a2); a2 = fmaf(w2.w, x3, a2);
        a3 = fmaf(w3.x, x0, a3); a3 = fmaf(w3.y, x1, a3); a3 = fmaf(w3.z, x2, a3); a3 = fmaf(w3.w, x3, a3);
        a4 = fmaf(w4.x, x0, a4); a4 = fmaf(w4.y, x1, a4); a4 = fmaf(w4.z, x2, a4); a4 = fmaf(w4.w, x3, a4);
        a5 = fmaf(w5.x, x0, a5); a5 = fmaf(w5.y, x1, a5); a5 = fmaf(w5.z, x2, a5); a5 = fmaf(w5.w, x3, a5);
      }
      int y = n / 100, xq = n % 100;
      float sy = fminf(fmaxf((y + 0.5f) * 0.5f - 0.5f, 0.0f), 49.0f);
      float sx = fminf(fmaxf((xq + 0.5f) * 0.5f - 0.5f, 0.0f), 49.0f);
      int y0 = (int)floorf(sy); int y1 = min(y0 + 1, 49); float ty = sy - (float)y0;
      int x0i = (int)floorf(sx); int x1i = min(x0i + 1, 49); float tx = sx - (float)x0i;
      float pd[6];
#pragma unroll
      for (int o = 0; o < 6; ++o) {
        const float* m = P.wpe + o * 2500;
        float v00 = m[y0 * 50 + x0i], v01 = m[y0 * 50 + x1i];
        float v10 = m[y1 * 50 + x0i], v11 = m[y1 * 50 + x1i];
        float r0 = v00 * (1.0f - ty) + v10 * ty;
        float r1 = v01 * (1.0f - ty) + v11 * ty;
        pd[o] = r0 * (1.0f - tx) + r1 * tx;
      }
      float c0 = a0 + pd[0] + P.bc[0];
      float c1 = a1 + pd[1] + P.bc[1];
      float b0 = a2 + pd[2] + P.bb[0];
      float b1 = a3 + pd[3] + P.bb[1];
      float b2 = a4 + pd[4] + P.bb[2];
      float b3 = a5 + pd[5] + P.bb[3];
      size_t nb = (size_t)b * N_PIX + n;
      float2 cv; cv.x = c0; cv.y = c1;
      *(float2*)(P.cls + nb * 2) = cv;
      float4 bv; bv.x = b0; bv.y = b1; bv.z = b2; bv.w = b3;
      *(float4*)(P.bbox + nb * 4) = bv;
      float m0 = fmaxf(c0, c1);
      float e0 = expf(c0 - m0), e1 = expf(c1 - m0);
      P.conf[nb] = e1 / (e0 + e1);
    }
  }
  grid.sync();

  // ---- phase C1: chunked top-k (blocks 0..127), R5-verified body ----
  if (bid < 128) {
    auto& T = sm.t1;
    int wv = tid >> 6;
    int b = bid >> 3, chunk = bid & 7;
    int base = chunk * 1250;
    const float* cb = P.conf + (size_t)b * N_PIX + base;
    for (int i = tid; i < 1250; i += 256) {
      unsigned int u = __float_as_uint(cb[i]);
      T.ordl[i] = (u & 0x80000000u) ? ~u : (u | 0x80000000u);
    }
    unsigned int prefix = 0, cnt_gt = 0;
    for (int pass = 0; pass < 4; ++pass) {
      int sh = 24 - 8 * pass;
      for (int i = tid; i < 4 * 256; i += 256) ((unsigned int*)T.whist)[i] = 0;
      __syncthreads();
      unsigned int himask = (pass == 0) ? 0u : (0xFFFFFFFFu << (sh + 8));
      for (int i = tid; i < 1250; i += 256) {
        unsigned int o = T.ordl[i];
        if ((o & himask) == prefix) atomicAdd(&T.whist[wv][(o >> sh) & 255u], 1u);
      }
      __syncthreads();
      if (tid < 256) {
        unsigned int s = T.whist[0][tid] + T.whist[1][tid] + T.whist[2][tid] + T.whist[3][tid];
        T.hist[tid] = s;
      }
      __syncthreads();
      if (tid == 0) {
        unsigned int c = cnt_gt; int v = 255;
        while (v > 0 && c + T.hist[v] < 100u) { c += T.hist[v]; --v; }
        T.s[0] = c; T.s[1] = prefix | ((unsigned int)v << sh);
      }
      __syncthreads();
      cnt_gt = T.s[0]; prefix = T.s[1];
      __syncthreads();
    }
    if (tid == 0) T.s[2] = 0;
    __syncthreads();
    unsigned int Th = prefix;
    unsigned long long* cb_out = P.candbuf + (size_t)(b * 8 + chunk) * 512;
    for (int i = tid; i < 1250; i += 256) {
      unsigned int o = T.ordl[i];
      if (o >= Th) {
        unsigned int k = atomicAdd(&T.s[2], 1u);
        if (k < 512u)
          cb_out[k] = ((unsigned long long)o << 32) |
                      (unsigned long long)(0xFFFFFFFFu - (unsigned int)(base + i));
      }
    }
    __syncthreads();
    if (tid == 0) P.cnt[b * 8 + chunk] = T.s[2] > 512u ? 512u : T.s[2];
  }
  grid.sync();

  // ---- phase C2: merge (blocks 0..15), R5-verified body ----
  if (bid < 16) {
    auto& T = sm.t2;
    int wv = tid >> 6;
    int b = bid;
    for (int s = tid; s < 4096; s += 256) {
      int ci = s >> 9, i = s & 511;
      unsigned int c = P.cnt[b * 8 + ci];
      T.keys[s] = ((unsigned int)i < c) ? P.candbuf[(size_t)(b * 8 + ci) * 512 + i] : 0ull;
    }
    __syncthreads();
    unsigned int prefix = 0, cnt_gt = 0;
    for (int pass = 0; pass < 4; ++pass) {
      int sh = 24 - 8 * pass;
      for (int i = tid; i < 4 * 256; i += 256) ((unsigned int*)T.whist)[i] = 0;
      __syncthreads();
      unsigned int himask = (pass == 0) ? 0u : (0xFFFFFFFFu << (sh + 8));
      for (int s = tid; s < 4096; s += 256) {
        unsigned int o = (unsigned int)(T.keys[s] >> 32);
        if ((o & himask) == prefix) atomicAdd(&T.whist[wv][(o >> sh) & 255u], 1u);
      }
      __syncthreads();
      if (tid < 256) {
        unsigned int s = T.whist[0][tid] + T.whist[1][tid] + T.whist[2][tid] + T.whist[3][tid];
        T.hist[tid] = s;
      }
      __syncthreads();
      if (tid == 0) {
        unsigned int c = cnt_gt; int v = 255;
        while (v > 0 && c + T.hist[v] < 100u) { c += T.hist[v]; --v; }
        T.s[0] = c; T.s[1] = prefix | ((unsigned int)v << sh);
      }
      __syncthreads();
      cnt_gt = T.s[0]; prefix = T.s[1];
      __syncthreads();
    }
    if (tid == 0) T.s[2] = 0;
    __syncthreads();
    unsigned int Th = prefix;
    for (int s = tid; s < 4096; s += 256) {
      unsigned int o = (unsigned int)(T.keys[s] >> 32);
      if (o >= Th) {
        unsigned int k = atomicAdd(&T.s[2], 1u);
        if (k < 256u) T.cand2[k] = T.keys[s];
      }
    }
    __syncthreads();
    unsigned int nc = T.s[2] > 256u ? 256u : T.s[2];
    if (tid >= (int)nc) T.cand2[tid] = 0ull;
    __syncthreads();
    for (unsigned int k = 2; k <= 256; k <<= 1) {
      for (unsigned int j = k >> 1; j > 0; j >>= 1) {
        unsigned int i = (unsigned int)tid, ixj = i ^ j;
        if (ixj > i) {
          unsigned long long a = T.cand2[i], c2 = T.cand2[ixj];
          bool up = ((i & k) == 0);
          if ((a > c2) == up) { T.cand2[i] = c2; T.cand2[ixj] = a; }
        }
        __syncthreads();
      }
    }
    if (tid < 100) {
      unsigned long long key = T.cand2[255 - tid];
      P.idx[b * 100 + tid] = (int)(0xFFFFFFFFu - (unsigned int)(key & 0xFFFFFFFFull));
    }
  }
  grid.sync();

  // ---- phase D: mlp (blocks 0..249), R7-verified body ----
  if (bid < 250) {
    int og = tid & 63, rg = tid >> 6;
    int base = bid * 8;
    bool is_det = base < 1600;
    const float *W1, *W2, *W3, *B1, *B2, *B3;
    if (is_det) {
      W1 = P.wT;          W2 = P.wT + 65536;  W3 = P.wT + 131072;
      B1 = P.db1; B2 = P.db2; B3 = P.db3;
    } else {
      W1 = P.wT + 196608; W2 = P.wT + 262144; W3 = P.wT + 327680;
      B1 = P.rb1; B2 = P.rb2; B3 = P.rb3;
    }
    for (int lr = 0; lr < 8; ++lr) {
      int rowid = base + lr;
      int b, r;
      if (rowid < 1600) { b = rowid / 100; r = rowid % 100; }
      else { int t2 = rowid - 1600; b = t2 / 25; r = t2 % 25; }
      int n = P.idx[b * 100 + r];
      float pv = pos_bilinear(P.pe, tid, n);
      sm.mlp.A[lr][tid] = P.x[((size_t)b * C_DIM + tid) * N_PIX + n] + pv;
    }
    __syncthreads();
    int lr0 = rg * 2;
    mlp_layer8(sm.mlp.A, sm.mlp.B, W1, B1, true,  og, lr0);
    mlp_layer8(sm.mlp.B, sm.mlp.A, W2, B2, true,  og, lr0);
    mlp_layer8(sm.mlp.A, sm.mlp.B, W3, B3, false, og, lr0);
    for (int lr = 0; lr < 8; ++lr) {
      int rowid = base + lr;
      if (rowid < 1600) {
        int r = rowid % 100;
        P.det[(size_t)rowid * C_DIM + tid] = sm.mlp.B[lr][tid] + P.det_q[r * C_DIM + tid];
      } else {
        int t2 = rowid - 1600; int r = t2 % 25;
        P.rec[(size_t)t2 * C_DIM + tid] = sm.mlp.B[lr][tid] + P.rec_q[r * C_DIM + tid];
      }
    }
  }
}

// ================== standalone fallback kernels (R7-exact) ===============================
__global__ __launch_bounds__(256) void k_prep(
    const float* __restrict__ pe,
    const float* __restrict__ Wc, const float* __restrict__ Wb,
    const float* __restrict__ dW1, const float* __restrict__ dW2, const float* __restrict__ dW3,
    const float* __restrict__ rW1, const float* __restrict__ rW2, const float* __restrict__ rW3,
    float* __restrict__ wpe, float* __restrict__ wT) {
  __shared__ float tile[64][65];
  int tid = threadIdx.x;
  int bid = blockIdx.x;
  if (bid < 60) {
    int o = bid / 10;
    int p = (bid % 10) * 256 + tid;
    if (p >= 2500) return;
    const float* W = (o < 2) ? (Wc + o * C_DIM) : (Wb + (o - 2) * C_DIM);
    float acc = 0.f;
#pragma unroll 8
    for (int c = 0; c < C_DIM; ++c) acc = fmaf(W[c], pe[c * 2500 + p], acc);
    wpe[o * 2500 + p] = acc;
    return;
  }
  int t = bid - 60;
  int m = t >> 4;
  int tl = t & 15;
  int ty = tl >> 2, tx = tl & 3;
  const float* W;
  switch (m) {
    case 0: W = dW1; break;
    case 1: W = dW2; break;
    case 2: W = dW3; break;
    case 3: W = rW1; break;
    case 4: W = rW2; break;
    default: W = rW3; break;
  }
  int lane = tid & 63, rg = tid >> 6;
  for (int rr = rg; rr < 64; rr += 4)
    tile[rr][lane] = W[(size_t)(ty * 64 + rr) * 256 + tx * 64 + lane];
  __syncthreads();
  for (int rr = rg; rr < 64; rr += 4)
    wT[(size_t)m * 65536 + (size_t)(tx * 64 + rr) * 256 + ty * 64 + lane] = tile[lane][rr];
}

__global__ __launch_bounds__(256, 4) void k_heads(
    const float* __restrict__ x, const float* __restrict__ wpe,
    const float* __restrict__ Wc, const float* __restrict__ bc,
    const float* __restrict__ Wb, const float* __restrict__ bb,
    float* __restrict__ cls, float* __restrict__ bbox, float* __restrict__ conf) {
  __shared__ float w[6][C_DIM];
  int tid = threadIdx.x;
  w[0][tid] = Wc[tid];
  w[1][tid] = Wc[C_DIM + tid];
  w[2][tid] = Wb[tid];
  w[3][tid] = Wb[C_DIM + tid];
  w[4][tid] = Wb[2 * C_DIM + tid];
  w[5][tid] = Wb[3 * C_DIM + tid];
  __syncthreads();
  int b = blockIdx.y;
  int n = blockIdx.x * 256 + tid;
  if (n >= N_PIX) return;
  const float* xb = x + (size_t)b * C_DIM * N_PIX + n;
  float a0 = 0.f, a1 = 0.f, a2 = 0.f, a3 = 0.f, a4 = 0.f, a5 = 0.f;
#pragma unroll 4
  for (int c = 0; c < C_DIM; c += 4) {
    float x0 = xb[(size_t)(c + 0) * N_PIX];
    float x1 = xb[(size_t)(c + 1) * N_PIX];
    float x2 = xb[(size_t)(c + 2) * N_PIX];
    float x3 = xb[(size_t)(c + 3) * N_PIX];
    float4 w0 = *(const float4*)(&w[0][c]);
    float4 w1 = *(const float4*)(&w[1][c]);
    float4 w2 = *(const float4*)(&w[2][c]);
    float4 w3 = *(const float4*)(&w[3][c]);
    float4 w4 = *(const float4*)(&w[4][c]);
    float4 w5 = *(const float4*)(&w[5][c]);
    a0 = fmaf(w0.x, x0, a0); a0 = fmaf(w0.y, x1, a0); a0 = fmaf(w0.z, x2, a0); a0 = fmaf(w0.w, x3, a0);
    a1 = fmaf(w1.x, x0, a1); a1 = fmaf(w1.y, x1, a1); a1 = fmaf(w1.z, x2, a1); a1 = fmaf(w1.w, x3, a1);
    a2 = fmaf(w2.x, x0, a2); a2 = fmaf(w2.y, x1, a2); a2 = fmaf(w2.z, x2, a2); a2 = fmaf(w2.w, x3, a2);
    a3 = fmaf(w3.x, x0, a3); a3 = fmaf(w3.y, x1, a3); a3 = fmaf(w3.z, x2, a3); a3 = fmaf(w3.w, x3, a3);
    a4 = fmaf(w4.x, x0, a4); a4 = fmaf(w4.y, x1, a4); a4 = fmaf(w4.z, x2, a4); a4 = fmaf(w4.w, x3, a4);
    a5 = fmaf(w5.x, x0, a5); a5 = fmaf(w5.y, x1, a5); a5 = fmaf(w5.z, x2, a5); a5 = fmaf(w5.w, x3, a5);
  }
  int y = n / 100, xq = n % 100;
  float sy = fminf(fmaxf((y + 0.5f) * 0.5f - 0.5f, 0.0f), 49.0f);
  float sx = fminf(fmaxf((xq + 0.5f) * 0.5f - 0.5f, 0.0f), 49.0f);
  int y0 = (int)floorf(sy); int y1 = min(y0 + 1, 49); float ty = sy - (float)y0;
  int x0i = (int)floorf(sx); int x1i = min(x0i + 1, 49); float tx = sx - (float)x0i;
  float pd[6];
#pragma unroll
  for (int o = 0; o < 6; ++o) {
    const float* m = wpe + o * 2500;
    float v00 = m[y0 * 50 + x0i], v01 = m[y0 * 50 + x1i];
    float v10 = m[y1 * 50 + x0i], v11 = m[y1 * 50 + x1i];
    float r0 = v00 * (1.0f - ty) + v10 * ty;
    float r1 = v01 * (1.0f - ty) + v11 * ty;
    pd[o] = r0 * (1.0f - tx) + r1 * tx;
  }
  float c0 = a0 + pd[0] + bc[0];
  float c1 = a1 + pd[1] + bc[1];
  float b0 = a2 + pd[2] + bb[0];
  float b1 = a3 + pd[3] + bb[1];
  float b2 = a4 + pd[4] + bb[2];
  float b3 = a5 + pd[5] + bb[3];
  size_t nb = (size_t)b * N_PIX + n;
  float2 cv; cv.x = c0; cv.y = c1;
  *(float2*)(cls + nb * 2) = cv;
  float4 bv; bv.x = b0; bv.y = b1; bv.z = b2; bv.w = b3;
  *(float4*)(bbox + nb * 4) = bv;
  float m0 = fmaxf(c0, c1);
  float e0 = expf(c0 - m0), e1 = expf(c1 - m0);
  conf[nb] = e1 / (e0 + e1);
}

__global__ __launch_bounds__(1024) void k_topk(const float* __restrict__ conf,
                                               int* __restrict__ idx_out) {
  __shared__ unsigned int ord[N_PIX];
  __shared__ unsigned int whist[16][256];
  __shared__ unsigned int hist[256];
  __shared__ unsigned long long cand[512];
  __shared__ unsigned int s_cnt, s_prefix, s_ncand;
  int tid = threadIdx.x;
  int wv = tid >> 6;
  int b = blockIdx.x;
  const float* cb = conf + (size_t)b * N_PIX;
  for (int i = tid; i < N_PIX; i += 1024) {
    unsigned int u = __float_as_uint(cb[i]);
    ord[i] = (u & 0x80000000u) ? ~u : (u | 0x80000000u);
  }
  unsigned int prefix = 0, cnt_gt = 0;
  for (int pass = 0; pass < 4; ++pass) {
    int sh = 24 - 8 * pass;
    for (int i = tid; i < 16 * 256; i += 1024) ((unsigned int*)whist)[i] = 0;
    __syncthreads();
    unsigned int himask = (pass == 0) ? 0u : (0xFFFFFFFFu << (sh + 8));
    for (int i = tid; i < N_PIX; i += 1024) {
      unsigned int o = ord[i];
      if ((o & himask) == prefix) atomicAdd(&whist[wv][(o >> sh) & 255u], 1u);
    }
    __syncthreads();
    if (tid < 256) {
      unsigned int s = 0;
#pragma unroll
      for (int w2 = 0; w2 < 16; ++w2) s += whist[w2][tid];
      hist[tid] = s;
    }
    __syncthreads();
    if (tid == 0) {
      unsigned int c = cnt_gt; int v = 255;
      while (v > 0 && c + hist[v] < 100u) { c += hist[v]; --v; }
      s_cnt = c; s_prefix = prefix | ((unsigned int)v << sh);
    }
    __syncthreads();
    cnt_gt = s_cnt; prefix = s_prefix;
    __syncthreads();
  }
  if (tid == 0) s_ncand = 0;
  __syncthreads();
  unsigned int T = prefix;
  for (int i = tid; i < N_PIX; i += 1024) {
    unsigned int o = ord[i];
    if (o >= T) {
      unsigned int k = atomicAdd(&s_ncand, 1u);
      if (k < 512u)
        cand[k] = ((unsigned long long)o << 32) |
                  (unsigned long long)(0xFFFFFFFFu - (unsigned int)i);
    }
  }
  __syncthreads();
  unsigned int nc = s_ncand > 512u ? 512u : s_ncand;
  for (int i = tid; i < 512; i += 1024)
    if ((unsigned int)i >= nc) cand[i] = 0ull;
  __syncthreads();
  for (unsigned int k = 2; k <= 512; k <<= 1) {
    for (unsigned int j = k >> 1; j > 0; j >>= 1) {
      if (tid < 512) {
        unsigned int i = (unsigned int)tid, ixj = i ^ j;
        if (ixj > i) {
          unsigned long long a = cand[i], c2 = cand[ixj];
          bool up = ((i & k) == 0);
          if ((a > c2) == up) { cand[i] = c2; cand[ixj] = a; }
        }
      }
      __syncthreads();
    }
  }
  if (tid < 100) {
    unsigned long long key = cand[511 - tid];
    idx_out[b * 100 + tid] = (int)(0xFFFFFFFFu - (unsigned int)(key & 0xFFFFFFFFull));
  }
}

__global__ __launch_bounds__(256) void k_mlp3(
    const float* __restrict__ x, const float* __restrict__ pe, const int* __restrict__ idx,
    const float* __restrict__ wT,
    const float* __restrict__ db1, const float* __restrict__ db2, const float* __restrict__ db3,
    const float* __restrict__ rb1, const float* __restrict__ rb2, const float* __restrict__ rb3,
    const float* __restrict__ det_q, const float* __restrict__ rec_q,
    float* __restrict__ det, float* __restrict__ rec) {
  __shared__ float bufA[8][C_DIM];
  __shared__ float bufB[8][C_DIM];
  int tid = threadIdx.x;
  int og = tid & 63, rg = tid >> 6;
  int base = blockIdx.x * 8;
  bool is_det = base < 1600;
  const float *W1, *W2, *W3, *B1, *B2, *B3;
  if (is_det) {
    W1 = wT;          W2 = wT + 65536;  W3 = wT + 131072;
    B1 = db1; B2 = db2; B3 = db3;
  } else {
    W1 = wT + 196608; W2 = wT + 262144; W3 = wT + 327680;
    B1 = rb1; B2 = rb2; B3 = rb3;
  }
  for (int lr = 0; lr < 8; ++lr) {
    int rowid = base + lr;
    int b, r;
    if (rowid < 1600) { b = rowid / 100; r = rowid % 100; }
    else { int t2 = rowid - 1600; b = t2 / 25; r = t2 % 25; }
    int n = idx[b * 100 + r];
    float pv = pos_bilinear(pe, tid, n);
    bufA[lr][tid] = x[((size_t)b * C_DIM + tid) * N_PIX + n] + pv;
  }
  __syncthreads();
  int lr0 = rg * 2;
  mlp_layer8(bufA, bufB, W1, B1, true,  og, lr0);
  mlp_layer8(bufB, bufA, W2, B2, true,  og, lr0);
  mlp_layer8(bufA, bufB, W3, B3, false, og, lr0);
  for (int lr = 0; lr < 8; ++lr) {
    int rowid = base + lr;
    if (rowid < 1600) {
      int r = rowid % 100;
      det[(size_t)rowid * C_DIM + tid] = bufB[lr][tid] + det_q[r * C_DIM + tid];
    } else {
      int t2 = rowid - 1600; int r = t2 % 25;
      rec[(size_t)t2 * C_DIM + tid] = bufB[lr][tid] + rec_q[r * C_DIM + tid];
    }
  }
}

extern "C" void kernel_launch(void* const* d_in, const int* in_sizes, int n_in,
                              void* d_out, int out_size, void* d_ws, size_t ws_size,
                              hipStream_t stream) {
  const float* x     = (const float*)d_in[0];
  const float* Wc    = (const float*)d_in[1];
  const float* bc    = (const float*)d_in[2];
  const float* Wb    = (const float*)d_in[3];
  const float* bb    = (const float*)d_in[4];
  const float* dW1   = (const float*)d_in[5];
  const float* db1   = (const float*)d_in[6];
  const float* dW2   = (const float*)d_in[7];
  const float* db2   = (const float*)d_in[8];
  const float* dW3   = (const float*)d_in[9];
  const float* db3   = (const float*)d_in[10];
  const float* rW1   = (const float*)d_in[11];
  const float* rb1   = (const float*)d_in[12];
  const float* rW2   = (const float*)d_in[13];
  const float* rb2   = (const float*)d_in[14];
  const float* rW3   = (const float*)d_in[15];
  const float* rb3   = (const float*)d_in[16];
  const float* det_q = (const float*)d_in[17];
  const float* rec_q = (const float*)d_in[18];
  const float* pos_e = (const float*)d_in[19];

  float* out  = (float*)d_out;
  float* det  = out;                // [16,100,256]
  float* rec  = out + 409600;       // [16, 25,256]
  float* cls  = out + 512000;       // [16,10000,2]
  float* bbox = out + 832000;       // [16,10000,4]

  // ws layout (bytes): candbuf @0 (524288) | wT @524288 (1572864) | conf @2097152 (640000)
  //                    idx @2737152 (8192) | wpe @2745344 (60000) | cnt @2805344 (512)
  char* wsb = (char*)d_ws;
  unsigned long long* candbuf = (unsigned long long*)wsb;
  float* wT   = (float*)(wsb + 524288);
  float* conf = (float*)(wsb + 2097152);
  int*   idx  = (int*)(wsb + 2737152);
  float* wpe  = (float*)(wsb + 2745344);
  unsigned int* cnt = (unsigned int*)(wsb + 2805344);

  KParams p;
  p.x = x; p.Wc = Wc; p.bc = bc; p.Wb = Wb; p.bb = bb;
  p.dW1 = dW1; p.db1 = db1; p.dW2 = dW2; p.db2 = db2; p.dW3 = dW3; p.db3 = db3;
  p.rW1 = rW1; p.rb1 = rb1; p.rW2 = rW2; p.rb2 = rb2; p.rW3 = rW3; p.rb3 = rb3;
  p.det_q = det_q; p.rec_q = rec_q; p.pe = pos_e;
  p.cls = cls; p.bbox = bbox; p.conf = conf; p.wpe = wpe; p.wT = wT;
  p.det = det; p.rec = rec;
  p.candbuf = candbuf; p.cnt = cnt; p.idx = idx;

  void* args[] = { &p };
  hipError_t e = hipLaunchCooperativeKernel((const void*)k_fused, dim3(512), dim3(256),
                                            args, 0, stream);
  if (e != hipSuccess) {
    (void)hipGetLastError();  // clear error state; fall back to 4-kernel pipeline (R7)
    k_prep<<<156, 256, 0, stream>>>(pos_e, Wc, Wb, dW1, dW2, dW3, rW1, rW2, rW3, wpe, wT);
    k_heads<<<dim3(40, B_SZ), 256, 0, stream>>>(x, wpe, Wc, bc, Wb, bb, cls, bbox, conf);
    k_topk<<<B_SZ, 1024, 0, stream>>>(conf, idx);
    k_mlp3<<<250, 256, 0, stream>>>(x, pos_e, idx, wT,
                                    db1, db2, db3, rb1, rb2, rb3,
                                    det_q, rec_q, det, rec);
  }
}

// Round 9
// 135.683 us; speedup vs baseline: 3.0214x; 3.0214x over previous
//
#include <hip/hip_runtime.h>
#include <cstdint>
#include <cstddef>

#define C_DIM 256
#define N_PIX 10000
#define B_SZ 16

// ---------------- k_prep (R7-exact): wpe (0..59) + tiled weight transpose (60..155) -----
__global__ __launch_bounds__(256) void k_prep(
    const float* __restrict__ pe,
    const float* __restrict__ Wc, const float* __restrict__ Wb,
    const float* __restrict__ dW1, const float* __restrict__ dW2, const float* __restrict__ dW3,
    const float* __restrict__ rW1, const float* __restrict__ rW2, const float* __restrict__ rW3,
    float* __restrict__ wpe, float* __restrict__ wT) {
  __shared__ float tile[64][65];
  int tid = threadIdx.x;
  int bid = blockIdx.x;
  if (bid < 60) {
    int o = bid / 10;
    int p = (bid % 10) * 256 + tid;
    if (p >= 2500) return;
    const float* W = (o < 2) ? (Wc + o * C_DIM) : (Wb + (o - 2) * C_DIM);
    float acc = 0.f;
#pragma unroll 8
    for (int c = 0; c < C_DIM; ++c) acc = fmaf(W[c], pe[c * 2500 + p], acc);
    wpe[o * 2500 + p] = acc;
    return;
  }
  int t = bid - 60;
  int m = t >> 4;
  int tl = t & 15;
  int ty = tl >> 2, tx = tl & 3;
  const float* W;
  switch (m) {
    case 0: W = dW1; break;
    case 1: W = dW2; break;
    case 2: W = dW3; break;
    case 3: W = rW1; break;
    case 4: W = rW2; break;
    default: W = rW3; break;
  }
  int lane = tid & 63, rg = tid >> 6;
  for (int rr = rg; rr < 64; rr += 4)
    tile[rr][lane] = W[(size_t)(ty * 64 + rr) * 256 + tx * 64 + lane];
  __syncthreads();
  for (int rr = rg; rr < 64; rr += 4)
    wT[(size_t)m * 65536 + (size_t)(tx * 64 + rr) * 256 + ty * 64 + lane] = tile[lane][rr];
}

// ---------------- fused cls/bbox/conf over x (R7-exact) ---------------------------------
__global__ __launch_bounds__(256, 4) void k_heads(
    const float* __restrict__ x, const float* __restrict__ wpe,
    const float* __restrict__ Wc, const float* __restrict__ bc,
    const float* __restrict__ Wb, const float* __restrict__ bb,
    float* __restrict__ cls, float* __restrict__ bbox, float* __restrict__ conf) {
  __shared__ float w[6][C_DIM];
  int tid = threadIdx.x;
  w[0][tid] = Wc[tid];
  w[1][tid] = Wc[C_DIM + tid];
  w[2][tid] = Wb[tid];
  w[3][tid] = Wb[C_DIM + tid];
  w[4][tid] = Wb[2 * C_DIM + tid];
  w[5][tid] = Wb[3 * C_DIM + tid];
  __syncthreads();
  int b = blockIdx.y;
  int n = blockIdx.x * 256 + tid;
  if (n >= N_PIX) return;
  const float* xb = x + (size_t)b * C_DIM * N_PIX + n;
  float a0 = 0.f, a1 = 0.f, a2 = 0.f, a3 = 0.f, a4 = 0.f, a5 = 0.f;
#pragma unroll 4
  for (int c = 0; c < C_DIM; c += 4) {
    float x0 = xb[(size_t)(c + 0) * N_PIX];
    float x1 = xb[(size_t)(c + 1) * N_PIX];
    float x2 = xb[(size_t)(c + 2) * N_PIX];
    float x3 = xb[(size_t)(c + 3) * N_PIX];
    float4 w0 = *(const float4*)(&w[0][c]);
    float4 w1 = *(const float4*)(&w[1][c]);
    float4 w2 = *(const float4*)(&w[2][c]);
    float4 w3 = *(const float4*)(&w[3][c]);
    float4 w4 = *(const float4*)(&w[4][c]);
    float4 w5 = *(const float4*)(&w[5][c]);
    a0 = fmaf(w0.x, x0, a0); a0 = fmaf(w0.y, x1, a0); a0 = fmaf(w0.z, x2, a0); a0 = fmaf(w0.w, x3, a0);
    a1 = fmaf(w1.x, x0, a1); a1 = fmaf(w1.y, x1, a1); a1 = fmaf(w1.z, x2, a1); a1 = fmaf(w1.w, x3, a1);
    a2 = fmaf(w2.x, x0, a2); a2 = fmaf(w2.y, x1, a2); a2 = fmaf(w2.z, x2, a2); a2 = fmaf(w2.w, x3, a2);
    a3 = fmaf(w3.x, x0, a3); a3 = fmaf(w3.y, x1, a3); a3 = fmaf(w3.z, x2, a3); a3 = fmaf(w3.w, x3, a3);
    a4 = fmaf(w4.x, x0, a4); a4 = fmaf(w4.y, x1, a4); a4 = fmaf(w4.z, x2, a4); a4 = fmaf(w4.w, x3, a4);
    a5 = fmaf(w5.x, x0, a5); a5 = fmaf(w5.y, x1, a5); a5 = fmaf(w5.z, x2, a5); a5 = fmaf(w5.w, x3, a5);
  }
  int y = n / 100, xq = n % 100;
  float sy = fminf(fmaxf((y + 0.5f) * 0.5f - 0.5f, 0.0f), 49.0f);
  float sx = fminf(fmaxf((xq + 0.5f) * 0.5f - 0.5f, 0.0f), 49.0f);
  int y0 = (int)floorf(sy); int y1 = min(y0 + 1, 49); float ty = sy - (float)y0;
  int x0i = (int)floorf(sx); int x1i = min(x0i + 1, 49); float tx = sx - (float)x0i;
  float pd[6];
#pragma unroll
  for (int o = 0; o < 6; ++o) {
    const float* m = wpe + o * 2500;
    float v00 = m[y0 * 50 + x0i], v01 = m[y0 * 50 + x1i];
    float v10 = m[y1 * 50 + x0i], v11 = m[y1 * 50 + x1i];
    float r0 = v00 * (1.0f - ty) + v10 * ty;
    float r1 = v01 * (1.0f - ty) + v11 * ty;
    pd[o] = r0 * (1.0f - tx) + r1 * tx;
  }
  float c0 = a0 + pd[0] + bc[0];
  float c1 = a1 + pd[1] + bc[1];
  float b0 = a2 + pd[2] + bb[0];
  float b1 = a3 + pd[3] + bb[1];
  float b2 = a4 + pd[4] + bb[2];
  float b3 = a5 + pd[5] + bb[3];
  size_t nb = (size_t)b * N_PIX + n;
  float2 cv; cv.x = c0; cv.y = c1;
  *(float2*)(cls + nb * 2) = cv;
  float4 bv; bv.x = b0; bv.y = b1; bv.z = b2; bv.w = b3;
  *(float4*)(bbox + nb * 4) = bv;
  float m0 = fmaxf(c0, c1);
  float e0 = expf(c0 - m0), e1 = expf(c1 - m0);
  conf[nb] = e1 / (e0 + e1);
}

// ---------------- per-batch top-100 (R7-exact) ------------------------------------------
__global__ __launch_bounds__(1024) void k_topk(const float* __restrict__ conf,
                                               int* __restrict__ idx_out) {
  __shared__ unsigned int ord[N_PIX];
  __shared__ unsigned int whist[16][256];
  __shared__ unsigned int hist[256];
  __shared__ unsigned long long cand[512];
  __shared__ unsigned int s_cnt, s_prefix, s_ncand;
  int tid = threadIdx.x;
  int wv = tid >> 6;
  int b = blockIdx.x;
  const float* cb = conf + (size_t)b * N_PIX;
  for (int i = tid; i < N_PIX; i += 1024) {
    unsigned int u = __float_as_uint(cb[i]);
    ord[i] = (u & 0x80000000u) ? ~u : (u | 0x80000000u);
  }
  unsigned int prefix = 0, cnt_gt = 0;
  for (int pass = 0; pass < 4; ++pass) {
    int sh = 24 - 8 * pass;
    for (int i = tid; i < 16 * 256; i += 1024) ((unsigned int*)whist)[i] = 0;
    __syncthreads();
    unsigned int himask = (pass == 0) ? 0u : (0xFFFFFFFFu << (sh + 8));
    for (int i = tid; i < N_PIX; i += 1024) {
      unsigned int o = ord[i];
      if ((o & himask) == prefix) atomicAdd(&whist[wv][(o >> sh) & 255u], 1u);
    }
    __syncthreads();
    if (tid < 256) {
      unsigned int s = 0;
#pragma unroll
      for (int w2 = 0; w2 < 16; ++w2) s += whist[w2][tid];
      hist[tid] = s;
    }
    __syncthreads();
    if (tid == 0) {
      unsigned int c = cnt_gt; int v = 255;
      while (v > 0 && c + hist[v] < 100u) { c += hist[v]; --v; }
      s_cnt = c; s_prefix = prefix | ((unsigned int)v << sh);
    }
    __syncthreads();
    cnt_gt = s_cnt; prefix = s_prefix;
    __syncthreads();
  }
  if (tid == 0) s_ncand = 0;
  __syncthreads();
  unsigned int T = prefix;
  for (int i = tid; i < N_PIX; i += 1024) {
    unsigned int o = ord[i];
    if (o >= T) {
      unsigned int k = atomicAdd(&s_ncand, 1u);
      if (k < 512u)
        cand[k] = ((unsigned long long)o << 32) |
                  (unsigned long long)(0xFFFFFFFFu - (unsigned int)i);
    }
  }
  __syncthreads();
  unsigned int nc = s_ncand > 512u ? 512u : s_ncand;
  for (int i = tid; i < 512; i += 1024)
    if ((unsigned int)i >= nc) cand[i] = 0ull;
  __syncthreads();
  for (unsigned int k = 2; k <= 512; k <<= 1) {
    for (unsigned int j = k >> 1; j > 0; j >>= 1) {
      if (tid < 512) {
        unsigned int i = (unsigned int)tid, ixj = i ^ j;
        if (ixj > i) {
          unsigned long long a = cand[i], c2 = cand[ixj];
          bool up = ((i & k) == 0);
          if ((a > c2) == up) { cand[i] = c2; cand[ixj] = a; }
        }
      }
      __syncthreads();
    }
  }
  if (tid < 100) {
    unsigned long long key = cand[511 - tid];
    idx_out[b * 100 + tid] = (int)(0xFFFFFFFFu - (unsigned int)(key & 0xFFFFFFFFull));
  }
}

// ---------------- k_mlp5: 4 rows/block (500 blocks), c-split over 4 waves ----------------
// Thread (og, rg): og = output quad (4 outs), rg = wave = c-quarter. Each block reads each
// weight matrix exactly once per layer (coalesced). Partials reduced via 16KB LDS buffer.
#define R4 4

__device__ __forceinline__ float pos_bilinear(const float* __restrict__ pe, int c, int n) {
  int y = n / 100, xq = n % 100;
  float sy = fminf(fmaxf((y + 0.5f) * 0.5f - 0.5f, 0.0f), 49.0f);
  float sx = fminf(fmaxf((xq + 0.5f) * 0.5f - 0.5f, 0.0f), 49.0f);
  int y0 = (int)floorf(sy); int y1 = min(y0 + 1, 49); float ty = sy - (float)y0;
  int x0i = (int)floorf(sx); int x1i = min(x0i + 1, 49); float tx = sx - (float)x0i;
  const float* p = pe + (size_t)c * 2500;
  float v00 = p[y0 * 50 + x0i], v01 = p[y0 * 50 + x1i];
  float v10 = p[y1 * 50 + x0i], v11 = p[y1 * 50 + x1i];
  float rr0 = v00 * (1.0f - ty) + v10 * ty;
  float rr1 = v01 * (1.0f - ty) + v11 * ty;
  return rr0 * (1.0f - tx) + rr1 * tx;
}

__device__ __forceinline__ void mlp_layer_cs(const float (*in)[C_DIM], float (*outb)[C_DIM],
    float (*red)[R4][C_DIM], const float* __restrict__ Wl, const float* __restrict__ bias,
    bool relu, int og, int rg, int tid) {
  float4 acc[R4];
#pragma unroll
  for (int r = 0; r < R4; ++r) { acc[r].x = 0.f; acc[r].y = 0.f; acc[r].z = 0.f; acc[r].w = 0.f; }
  int c0 = rg * 64;
#pragma unroll 4
  for (int ci = 0; ci < 64; ci += 4) {
    int c = c0 + ci;
    float4 w0 = *(const float4*)(Wl + (size_t)(c + 0) * C_DIM + og * 4);
    float4 w1 = *(const float4*)(Wl + (size_t)(c + 1) * C_DIM + og * 4);
    float4 w2 = *(const float4*)(Wl + (size_t)(c + 2) * C_DIM + og * 4);
    float4 w3 = *(const float4*)(Wl + (size_t)(c + 3) * C_DIM + og * 4);
#pragma unroll
    for (int r = 0; r < R4; ++r) {
      float4 iv = *(const float4*)(&in[r][c]);
      acc[r].x = fmaf(w0.x, iv.x, acc[r].x); acc[r].y = fmaf(w0.y, iv.x, acc[r].y);
      acc[r].z = fmaf(w0.z, iv.x, acc[r].z); acc[r].w = fmaf(w0.w, iv.x, acc[r].w);
      acc[r].x = fmaf(w1.x, iv.y, acc[r].x); acc[r].y = fmaf(w1.y, iv.y, acc[r].y);
      acc[r].z = fmaf(w1.z, iv.y, acc[r].z); acc[r].w = fmaf(w1.w, iv.y, acc[r].w);
      acc[r].x = fmaf(w2.x, iv.z, acc[r].x); acc[r].y = fmaf(w2.y, iv.z, acc[r].y);
      acc[r].z = fmaf(w2.z, iv.z, acc[r].z); acc[r].w = fmaf(w2.w, iv.z, acc[r].w);
      acc[r].x = fmaf(w3.x, iv.w, acc[r].x); acc[r].y = fmaf(w3.y, iv.w, acc[r].y);
      acc[r].z = fmaf(w3.z, iv.w, acc[r].z); acc[r].w = fmaf(w3.w, iv.w, acc[r].w);
    }
  }
#pragma unroll
  for (int r = 0; r < R4; ++r) *(float4*)(&red[rg][r][og * 4]) = acc[r];
  __syncthreads();
  // reduce 4 c-quarters; thread handles out=tid for all rows
#pragma unroll
  for (int r = 0; r < R4; ++r) {
    float s = red[0][r][tid] + red[1][r][tid] + red[2][r][tid] + red[3][r][tid] + bias[tid];
    outb[r][tid] = relu ? fmaxf(s, 0.f) : s;
  }
  __syncthreads();
}

__global__ __launch_bounds__(256, 2) void k_mlp5(
    const float* __restrict__ x, const float* __restrict__ pe, const int* __restrict__ idx,
    const float* __restrict__ wT,
    const float* __restrict__ db1, const float* __restrict__ db2, const float* __restrict__ db3,
    const float* __restrict__ rb1, const float* __restrict__ rb2, const float* __restrict__ rb3,
    const float* __restrict__ det_q, const float* __restrict__ rec_q,
    float* __restrict__ det, float* __restrict__ rec) {
  __shared__ float actA[R4][C_DIM];
  __shared__ float actB[R4][C_DIM];
  __shared__ float red[4][R4][C_DIM];
  int tid = threadIdx.x;
  int og = tid & 63, rg = tid >> 6;
  int base = blockIdx.x * R4;              // 500 blocks; det rows 0..1599, rec 1600..1999
  bool is_det = base < 1600;
  const float *W1, *W2, *W3, *B1, *B2, *B3;
  if (is_det) {
    W1 = wT;          W2 = wT + 65536;  W3 = wT + 131072;
    B1 = db1; B2 = db2; B3 = db3;
  } else {
    W1 = wT + 196608; W2 = wT + 262144; W3 = wT + 327680;
    B1 = rb1; B2 = rb2; B3 = rb3;
  }
#pragma unroll
  for (int lr = 0; lr < R4; ++lr) {
    int rowid = base + lr;
    int b, r;
    if (rowid < 1600) { b = rowid / 100; r = rowid % 100; }
    else { int t2 = rowid - 1600; b = t2 / 25; r = t2 % 25; }
    int n = idx[b * 100 + r];
    actA[lr][tid] = x[((size_t)b * C_DIM + tid) * N_PIX + n] + pos_bilinear(pe, tid, n);
  }
  __syncthreads();
  mlp_layer_cs(actA, actB, red, W1, B1, true,  og, rg, tid);
  mlp_layer_cs(actB, actA, red, W2, B2, true,  og, rg, tid);
  mlp_layer_cs(actA, actB, red, W3, B3, false, og, rg, tid);
#pragma unroll
  for (int lr = 0; lr < R4; ++lr) {
    int rowid = base + lr;
    if (rowid < 1600) {
      int r = rowid % 100;
      det[(size_t)rowid * C_DIM + tid] = actB[lr][tid] + det_q[r * C_DIM + tid];
    } else {
      int t2 = rowid - 1600; int r = t2 % 25;
      rec[(size_t)t2 * C_DIM + tid] = actB[lr][tid] + rec_q[r * C_DIM + tid];
    }
  }
}

extern "C" void kernel_launch(void* const* d_in, const int* in_sizes, int n_in,
                              void* d_out, int out_size, void* d_ws, size_t ws_size,
                              hipStream_t stream) {
  const float* x     = (const float*)d_in[0];
  const float* Wc    = (const float*)d_in[1];
  const float* bc    = (const float*)d_in[2];
  const float* Wb    = (const float*)d_in[3];
  const float* bb    = (const float*)d_in[4];
  const float* dW1   = (const float*)d_in[5];
  const float* db1   = (const float*)d_in[6];
  const float* dW2   = (const float*)d_in[7];
  const float* db2   = (const float*)d_in[8];
  const float* dW3   = (const float*)d_in[9];
  const float* db3   = (const float*)d_in[10];
  const float* rW1   = (const float*)d_in[11];
  const float* rb1   = (const float*)d_in[12];
  const float* rW2   = (const float*)d_in[13];
  const float* rb2   = (const float*)d_in[14];
  const float* rW3   = (const float*)d_in[15];
  const float* rb3   = (const float*)d_in[16];
  const float* det_q = (const float*)d_in[17];
  const float* rec_q = (const float*)d_in[18];
  const float* pos_e = (const float*)d_in[19];

  float* out  = (float*)d_out;
  float* det  = out;                // [16,100,256]
  float* rec  = out + 409600;       // [16, 25,256]
  float* cls  = out + 512000;       // [16,10000,2]
  float* bbox = out + 832000;       // [16,10000,4]

  // ws layout (bytes): wT @0 (1572864) | conf @1572864 (640000) | idx @2212864 | wpe @2221056
  char* wsb = (char*)d_ws;
  float* wT   = (float*)wsb;
  float* conf = (float*)(wsb + 1572864);
  int*   idx  = (int*)(wsb + 2212864);
  float* wpe  = (float*)(wsb + 2221056);

  k_prep<<<156, 256, 0, stream>>>(pos_e, Wc, Wb, dW1, dW2, dW3, rW1, rW2, rW3, wpe, wT);
  k_heads<<<dim3(40, B_SZ), 256, 0, stream>>>(x, wpe, Wc, bc, Wb, bb, cls, bbox, conf);
  k_topk<<<B_SZ, 1024, 0, stream>>>(conf, idx);
  k_mlp5<<<500, 256, 0, stream>>>(x, pos_e, idx, wT,
                                  db1, db2, db3, rb1, rb2, rb3,
                                  det_q, rec_q, det, rec);
}

// Round 10
// 135.658 us; speedup vs baseline: 3.0219x; 1.0002x over previous
//
#include <hip/hip_runtime.h>
#include <cstdint>
#include <cstddef>

#define C_DIM 256
#define N_PIX 10000
#define B_SZ 16

// ---------------- k_prep (R9-exact): wpe (0..59) + tiled weight transpose (60..155) -----
__global__ __launch_bounds__(256) void k_prep(
    const float* __restrict__ pe,
    const float* __restrict__ Wc, const float* __restrict__ Wb,
    const float* __restrict__ dW1, const float* __restrict__ dW2, const float* __restrict__ dW3,
    const float* __restrict__ rW1, const float* __restrict__ rW2, const float* __restrict__ rW3,
    float* __restrict__ wpe, float* __restrict__ wT) {
  __shared__ float tile[64][65];
  int tid = threadIdx.x;
  int bid = blockIdx.x;
  if (bid < 60) {
    int o = bid / 10;
    int p = (bid % 10) * 256 + tid;
    if (p >= 2500) return;
    const float* W = (o < 2) ? (Wc + o * C_DIM) : (Wb + (o - 2) * C_DIM);
    float acc = 0.f;
#pragma unroll 8
    for (int c = 0; c < C_DIM; ++c) acc = fmaf(W[c], pe[c * 2500 + p], acc);
    wpe[o * 2500 + p] = acc;
    return;
  }
  int t = bid - 60;
  int m = t >> 4;
  int tl = t & 15;
  int ty = tl >> 2, tx = tl & 3;
  const float* W;
  switch (m) {
    case 0: W = dW1; break;
    case 1: W = dW2; break;
    case 2: W = dW3; break;
    case 3: W = rW1; break;
    case 4: W = rW2; break;
    default: W = rW3; break;
  }
  int lane = tid & 63, rg = tid >> 6;
  for (int rr = rg; rr < 64; rr += 4)
    tile[rr][lane] = W[(size_t)(ty * 64 + rr) * 256 + tx * 64 + lane];
  __syncthreads();
  for (int rr = rg; rr < 64; rr += 4)
    wT[(size_t)m * 65536 + (size_t)(tx * 64 + rr) * 256 + ty * 64 + lane] = tile[lane][rr];
}

// ---------------- k_heads2: scalar-cached weights (no LDS), 8 loads in flight -----------
__global__ __launch_bounds__(256, 4) void k_heads2(
    const float* __restrict__ x, const float* __restrict__ wpe,
    const float* __restrict__ Wc, const float* __restrict__ bc,
    const float* __restrict__ Wb, const float* __restrict__ bb,
    float* __restrict__ cls, float* __restrict__ bbox, float* __restrict__ conf) {
  int tid = threadIdx.x;
  int b = blockIdx.y;
  int n = blockIdx.x * 256 + tid;            // grid (40, 16)
  if (n >= N_PIX) return;
  const float* xb = x + (size_t)b * C_DIM * N_PIX + n;
  const float* w1p = Wc + C_DIM;
  const float* w2p = Wb;
  const float* w3p = Wb + C_DIM;
  const float* w4p = Wb + 2 * C_DIM;
  const float* w5p = Wb + 3 * C_DIM;
  float a0 = 0.f, a1 = 0.f, a2 = 0.f, a3 = 0.f, a4 = 0.f, a5 = 0.f;
  for (int c = 0; c < C_DIM; c += 8) {
    float xv0 = xb[(size_t)(c + 0) * N_PIX];
    float xv1 = xb[(size_t)(c + 1) * N_PIX];
    float xv2 = xb[(size_t)(c + 2) * N_PIX];
    float xv3 = xb[(size_t)(c + 3) * N_PIX];
    float xv4 = xb[(size_t)(c + 4) * N_PIX];
    float xv5 = xb[(size_t)(c + 5) * N_PIX];
    float xv6 = xb[(size_t)(c + 6) * N_PIX];
    float xv7 = xb[(size_t)(c + 7) * N_PIX];
#pragma unroll
    for (int j = 0; j < 8; ++j) {
      float xv = (j == 0) ? xv0 : (j == 1) ? xv1 : (j == 2) ? xv2 : (j == 3) ? xv3
               : (j == 4) ? xv4 : (j == 5) ? xv5 : (j == 6) ? xv6 : xv7;
      a0 = fmaf(Wc[c + j],  xv, a0);
      a1 = fmaf(w1p[c + j], xv, a1);
      a2 = fmaf(w2p[c + j], xv, a2);
      a3 = fmaf(w3p[c + j], xv, a3);
      a4 = fmaf(w4p[c + j], xv, a4);
      a5 = fmaf(w5p[c + j], xv, a5);
    }
  }
  int y = n / 100, xq = n % 100;
  float sy = fminf(fmaxf((y + 0.5f) * 0.5f - 0.5f, 0.0f), 49.0f);
  float sx = fminf(fmaxf((xq + 0.5f) * 0.5f - 0.5f, 0.0f), 49.0f);
  int y0 = (int)floorf(sy); int y1 = min(y0 + 1, 49); float ty = sy - (float)y0;
  int x0i = (int)floorf(sx); int x1i = min(x0i + 1, 49); float tx = sx - (float)x0i;
  float pd[6];
#pragma unroll
  for (int o = 0; o < 6; ++o) {
    const float* m = wpe + o * 2500;
    float v00 = m[y0 * 50 + x0i], v01 = m[y0 * 50 + x1i];
    float v10 = m[y1 * 50 + x0i], v11 = m[y1 * 50 + x1i];
    float r0 = v00 * (1.0f - ty) + v10 * ty;
    float r1 = v01 * (1.0f - ty) + v11 * ty;
    pd[o] = r0 * (1.0f - tx) + r1 * tx;
  }
  float c0 = a0 + pd[0] + bc[0];
  float c1 = a1 + pd[1] + bc[1];
  float b0 = a2 + pd[2] + bb[0];
  float b1 = a3 + pd[3] + bb[1];
  float b2 = a4 + pd[4] + bb[2];
  float b3 = a5 + pd[5] + bb[3];
  size_t nb = (size_t)b * N_PIX + n;
  float2 cv; cv.x = c0; cv.y = c1;
  *(float2*)(cls + nb * 2) = cv;
  float4 bv; bv.x = b0; bv.y = b1; bv.z = b2; bv.w = b3;
  *(float4*)(bbox + nb * 4) = bv;
  float m0 = fmaxf(c0, c1);
  float e0 = expf(c0 - m0), e1 = expf(c1 - m0);
  conf[nb] = e1 / (e0 + e1);
}

// ---------------- per-batch top-100 (R9-exact) ------------------------------------------
__global__ __launch_bounds__(1024) void k_topk(const float* __restrict__ conf,
                                               int* __restrict__ idx_out) {
  __shared__ unsigned int ord[N_PIX];
  __shared__ unsigned int whist[16][256];
  __shared__ unsigned int hist[256];
  __shared__ unsigned long long cand[512];
  __shared__ unsigned int s_cnt, s_prefix, s_ncand;
  int tid = threadIdx.x;
  int wv = tid >> 6;
  int b = blockIdx.x;
  const float* cb = conf + (size_t)b * N_PIX;
  for (int i = tid; i < N_PIX; i += 1024) {
    unsigned int u = __float_as_uint(cb[i]);
    ord[i] = (u & 0x80000000u) ? ~u : (u | 0x80000000u);
  }
  unsigned int prefix = 0, cnt_gt = 0;
  for (int pass = 0; pass < 4; ++pass) {
    int sh = 24 - 8 * pass;
    for (int i = tid; i < 16 * 256; i += 1024) ((unsigned int*)whist)[i] = 0;
    __syncthreads();
    unsigned int himask = (pass == 0) ? 0u : (0xFFFFFFFFu << (sh + 8));
    for (int i = tid; i < N_PIX; i += 1024) {
      unsigned int o = ord[i];
      if ((o & himask) == prefix) atomicAdd(&whist[wv][(o >> sh) & 255u], 1u);
    }
    __syncthreads();
    if (tid < 256) {
      unsigned int s = 0;
#pragma unroll
      for (int w2 = 0; w2 < 16; ++w2) s += whist[w2][tid];
      hist[tid] = s;
    }
    __syncthreads();
    if (tid == 0) {
      unsigned int c = cnt_gt; int v = 255;
      while (v > 0 && c + hist[v] < 100u) { c += hist[v]; --v; }
      s_cnt = c; s_prefix = prefix | ((unsigned int)v << sh);
    }
    __syncthreads();
    cnt_gt = s_cnt; prefix = s_prefix;
    __syncthreads();
  }
  if (tid == 0) s_ncand = 0;
  __syncthreads();
  unsigned int T = prefix;
  for (int i = tid; i < N_PIX; i += 1024) {
    unsigned int o = ord[i];
    if (o >= T) {
      unsigned int k = atomicAdd(&s_ncand, 1u);
      if (k < 512u)
        cand[k] = ((unsigned long long)o << 32) |
                  (unsigned long long)(0xFFFFFFFFu - (unsigned int)i);
    }
  }
  __syncthreads();
  unsigned int nc = s_ncand > 512u ? 512u : s_ncand;
  for (int i = tid; i < 512; i += 1024)
    if ((unsigned int)i >= nc) cand[i] = 0ull;
  __syncthreads();
  for (unsigned int k = 2; k <= 512; k <<= 1) {
    for (unsigned int j = k >> 1; j > 0; j >>= 1) {
      if (tid < 512) {
        unsigned int i = (unsigned int)tid, ixj = i ^ j;
        if (ixj > i) {
          unsigned long long a = cand[i], c2 = cand[ixj];
          bool up = ((i & k) == 0);
          if ((a > c2) == up) { cand[i] = c2; cand[ixj] = a; }
        }
      }
      __syncthreads();
    }
  }
  if (tid < 100) {
    unsigned long long key = cand[511 - tid];
    idx_out[b * 100 + tid] = (int)(0xFFFFFFFFu - (unsigned int)(key & 0xFFFFFFFFull));
  }
}

// ---------------- k_mlp5 (R9-exact): 4 rows/block, c-split over 4 waves ------------------
#define R4 4

__device__ __forceinline__ float pos_bilinear(const float* __restrict__ pe, int c, int n) {
  int y = n / 100, xq = n % 100;
  float sy = fminf(fmaxf((y + 0.5f) * 0.5f - 0.5f, 0.0f), 49.0f);
  float sx = fminf(fmaxf((xq + 0.5f) * 0.5f - 0.5f, 0.0f), 49.0f);
  int y0 = (int)floorf(sy); int y1 = min(y0 + 1, 49); float ty = sy - (float)y0;
  int x0i = (int)floorf(sx); int x1i = min(x0i + 1, 49); float tx = sx - (float)x0i;
  const float* p = pe + (size_t)c * 2500;
  float v00 = p[y0 * 50 + x0i], v01 = p[y0 * 50 + x1i];
  float v10 = p[y1 * 50 + x0i], v11 = p[y1 * 50 + x1i];
  float rr0 = v00 * (1.0f - ty) + v10 * ty;
  float rr1 = v01 * (1.0f - ty) + v11 * ty;
  return rr0 * (1.0f - tx) + rr1 * tx;
}

__device__ __forceinline__ void mlp_layer_cs(const float (*in)[C_DIM], float (*outb)[C_DIM],
    float (*red)[R4][C_DIM], const float* __restrict__ Wl, const float* __restrict__ bias,
    bool relu, int og, int rg, int tid) {
  float4 acc[R4];
#pragma unroll
  for (int r = 0; r < R4; ++r) { acc[r].x = 0.f; acc[r].y = 0.f; acc[r].z = 0.f; acc[r].w = 0.f; }
  int c0 = rg * 64;
#pragma unroll 4
  for (int ci = 0; ci < 64; ci += 4) {
    int c = c0 + ci;
    float4 w0 = *(const float4*)(Wl + (size_t)(c + 0) * C_DIM + og * 4);
    float4 w1 = *(const float4*)(Wl + (size_t)(c + 1) * C_DIM + og * 4);
    float4 w2 = *(const float4*)(Wl + (size_t)(c + 2) * C_DIM + og * 4);
    float4 w3 = *(const float4*)(Wl + (size_t)(c + 3) * C_DIM + og * 4);
#pragma unroll
    for (int r = 0; r < R4; ++r) {
      float4 iv = *(const float4*)(&in[r][c]);
      acc[r].x = fmaf(w0.x, iv.x, acc[r].x); acc[r].y = fmaf(w0.y, iv.x, acc[r].y);
      acc[r].z = fmaf(w0.z, iv.x, acc[r].z); acc[r].w = fmaf(w0.w, iv.x, acc[r].w);
      acc[r].x = fmaf(w1.x, iv.y, acc[r].x); acc[r].y = fmaf(w1.y, iv.y, acc[r].y);
      acc[r].z = fmaf(w1.z, iv.y, acc[r].z); acc[r].w = fmaf(w1.w, iv.y, acc[r].w);
      acc[r].x = fmaf(w2.x, iv.z, acc[r].x); acc[r].y = fmaf(w2.y, iv.z, acc[r].y);
      acc[r].z = fmaf(w2.z, iv.z, acc[r].z); acc[r].w = fmaf(w2.w, iv.z, acc[r].w);
      acc[r].x = fmaf(w3.x, iv.w, acc[r].x); acc[r].y = fmaf(w3.y, iv.w, acc[r].y);
      acc[r].z = fmaf(w3.z, iv.w, acc[r].z); acc[r].w = fmaf(w3.w, iv.w, acc[r].w);
    }
  }
#pragma unroll
  for (int r = 0; r < R4; ++r) *(float4*)(&red[rg][r][og * 4]) = acc[r];
  __syncthreads();
#pragma unroll
  for (int r = 0; r < R4; ++r) {
    float s = red[0][r][tid] + red[1][r][tid] + red[2][r][tid] + red[3][r][tid] + bias[tid];
    outb[r][tid] = relu ? fmaxf(s, 0.f) : s;
  }
  __syncthreads();
}

__global__ __launch_bounds__(256, 2) void k_mlp5(
    const float* __restrict__ x, const float* __restrict__ pe, const int* __restrict__ idx,
    const float* __restrict__ wT,
    const float* __restrict__ db1, const float* __restrict__ db2, const float* __restrict__ db3,
    const float* __restrict__ rb1, const float* __restrict__ rb2, const float* __restrict__ rb3,
    const float* __restrict__ det_q, const float* __restrict__ rec_q,
    float* __restrict__ det, float* __restrict__ rec) {
  __shared__ float actA[R4][C_DIM];
  __shared__ float actB[R4][C_DIM];
  __shared__ float red[4][R4][C_DIM];
  int tid = threadIdx.x;
  int og = tid & 63, rg = tid >> 6;
  int base = blockIdx.x * R4;
  bool is_det = base < 1600;
  const float *W1, *W2, *W3, *B1, *B2, *B3;
  if (is_det) {
    W1 = wT;          W2 = wT + 65536;  W3 = wT + 131072;
    B1 = db1; B2 = db2; B3 = db3;
  } else {
    W1 = wT + 196608; W2 = wT + 262144; W3 = wT + 327680;
    B1 = rb1; B2 = rb2; B3 = rb3;
  }
#pragma unroll
  for (int lr = 0; lr < R4; ++lr) {
    int rowid = base + lr;
    int b, r;
    if (rowid < 1600) { b = rowid / 100; r = rowid % 100; }
    else { int t2 = rowid - 1600; b = t2 / 25; r = t2 % 25; }
    int n = idx[b * 100 + r];
    actA[lr][tid] = x[((size_t)b * C_DIM + tid) * N_PIX + n] + pos_bilinear(pe, tid, n);
  }
  __syncthreads();
  mlp_layer_cs(actA, actB, red, W1, B1, true,  og, rg, tid);
  mlp_layer_cs(actB, actA, red, W2, B2, true,  og, rg, tid);
  mlp_layer_cs(actA, actB, red, W3, B3, false, og, rg, tid);
#pragma unroll
  for (int lr = 0; lr < R4; ++lr) {
    int rowid = base + lr;
    if (rowid < 1600) {
      int r = rowid % 100;
      det[(size_t)rowid * C_DIM + tid] = actB[lr][tid] + det_q[r * C_DIM + tid];
    } else {
      int t2 = rowid - 1600; int r = t2 % 25;
      rec[(size_t)t2 * C_DIM + tid] = actB[lr][tid] + rec_q[r * C_DIM + tid];
    }
  }
}

extern "C" void kernel_launch(void* const* d_in, const int* in_sizes, int n_in,
                              void* d_out, int out_size, void* d_ws, size_t ws_size,
                              hipStream_t stream) {
  const float* x     = (const float*)d_in[0];
  const float* Wc    = (const float*)d_in[1];
  const float* bc    = (const float*)d_in[2];
  const float* Wb    = (const float*)d_in[3];
  const float* bb    = (const float*)d_in[4];
  const float* dW1   = (const float*)d_in[5];
  const float* db1   = (const float*)d_in[6];
  const float* dW2   = (const float*)d_in[7];
  const float* db2   = (const float*)d_in[8];
  const float* dW3   = (const float*)d_in[9];
  const float* db3   = (const float*)d_in[10];
  const float* rW1   = (const float*)d_in[11];
  const float* rb1   = (const float*)d_in[12];
  const float* rW2   = (const float*)d_in[13];
  const float* rb2   = (const float*)d_in[14];
  const float* rW3   = (const float*)d_in[15];
  const float* rb3   = (const float*)d_in[16];
  const float* det_q = (const float*)d_in[17];
  const float* rec_q = (const float*)d_in[18];
  const float* pos_e = (const float*)d_in[19];

  float* out  = (float*)d_out;
  float* det  = out;                // [16,100,256]
  float* rec  = out + 409600;       // [16, 25,256]
  float* cls  = out + 512000;       // [16,10000,2]
  float* bbox = out + 832000;       // [16,10000,4]

  // ws layout (bytes): wT @0 (1572864) | conf @1572864 (640000) | idx @2212864 | wpe @2221056
  char* wsb = (char*)d_ws;
  float* wT   = (float*)wsb;
  float* conf = (float*)(wsb + 1572864);
  int*   idx  = (int*)(wsb + 2212864);
  float* wpe  = (float*)(wsb + 2221056);

  k_prep<<<156, 256, 0, stream>>>(pos_e, Wc, Wb, dW1, dW2, dW3, rW1, rW2, rW3, wpe, wT);
  k_heads2<<<dim3(40, B_SZ), 256, 0, stream>>>(x, wpe, Wc, bc, Wb, bb, cls, bbox, conf);
  k_topk<<<B_SZ, 1024, 0, stream>>>(conf, idx);
  k_mlp5<<<500, 256, 0, stream>>>(x, pos_e, idx, wT,
                                  db1, db2, db3, rb1, rb2, rb3,
                                  det_q, rec_q, det, rec);
}